// Round 1
// 895.533 us; speedup vs baseline: 1.0877x; 1.0877x over previous
//
#include <hip/hip_runtime.h>
#include <math.h>

typedef unsigned short u16;
typedef unsigned int   u32;

#define B    128
#define H    1024
#define SEQ  512
#define VOUT 32000

#define NQ   4            // seq splits for flash attention
#define SQB  (SEQ / NQ)   // 128 seq positions per block
#define TS   8            // tile of seq rows staged in LDS
#define NT   (SQB / TS)   // 16 tiles per block

using bf16x8 = __attribute__((ext_vector_type(8))) short;
using f32x4  = __attribute__((ext_vector_type(4))) float;

__device__ __forceinline__ float b2f(u32 u){ return __uint_as_float((u & 0xffffu) << 16); }
__device__ __forceinline__ float sigm(float x){ return 1.0f / (1.0f + expf(-x)); }
__device__ __forceinline__ u32 cvt2(float a, float b){   // pack bf16(a) lo | bf16(b) hi, RNE
  u32 ua = __float_as_uint(a); ua += 0x7fffu + ((ua >> 16) & 1u);
  u32 ub = __float_as_uint(b); ub += 0x7fffu + ((ub >> 16) & 1u);
  return (ua >> 16) | (ub & 0xffff0000u);
}

// generic element load: bf=1 -> data is bf16 (u16); bf=0 -> data is f32
__device__ __forceinline__ float ldf(const void* p, size_t i, int bf){
  return bf ? b2f(((const u16*)p)[i]) : ((const float*)p)[i];
}

// ---- runtime input-dtype detection (1 = bf16, 0 = f32); proven: picks f32 here ----
__global__ void k_detect(const u16* __restrict__ enc, int* __restrict__ flag){
  __shared__ int cnt;
  if (threadIdx.x == 0) cnt = 0;
  __syncthreads();
  int c = 0;
  for (int j = threadIdx.x; j < 512; j += 256){
    u32 u = enc[j];
    u32 e = (u >> 7) & 0xFFu;
    c += (u == 0u || (e >= 100u && e <= 130u)) ? 1 : 0;
  }
  atomicAdd(&cnt, c);
  __syncthreads();
  if (threadIdx.x == 0) *flag = (cnt > 410) ? 1 : 0;
}

// ---- init: X = emb[idx], Hb = h1 (both f32 in ws) ----
__global__ void k_init(const int* __restrict__ idx, const void* __restrict__ emb,
                       const void* __restrict__ h1, float* __restrict__ X, float* __restrict__ Hb,
                       const int* __restrict__ flagp){
  int bf = *flagp;
  int t = blockIdx.x * 256 + threadIdx.x;   // B*H threads
  int b = t >> 10, h = t & (H - 1);
  X[t]  = ldf(emb, (size_t)idx[b] * H + h, bf);
  Hb[t] = ldf(h1, t, bf);
}

// ---- split-K GEMM: partial[b,n] = A[b, kbase:+Kc] @ W[n, kbase:+Kc]^T ----
// OUT 0: P[split] = partial      OUT 1: P[split] += partial
template<int OUT>
__global__ __launch_bounds__(256)
void gemm_s(const float* __restrict__ A, const void* __restrict__ W, size_t wOff,
            float* __restrict__ P, int K, int Kc, int N, const int* __restrict__ flagp)
{
  const int bf = *flagp;
  __shared__ float As[32][132];   // [k][b], padded
  __shared__ float Wt[32][68];    // [k][n], padded
  const int t  = threadIdx.x;
  const int n0 = blockIdx.x * 64;
  const int kbase = blockIdx.y * Kc;
  const int sb = t >> 1,  sk = (t & 1) << 4;
  const int wn = t >> 2,  wk = (t & 3) << 3;
  const int bx = (t & 15) << 3;
  const int ny = (t >> 4) << 2;

  float acc[8][4];
  #pragma unroll
  for (int i = 0; i < 8; ++i)
    #pragma unroll
    for (int j = 0; j < 4; ++j) acc[i][j] = 0.f;

  for (int k0 = 0; k0 < Kc; k0 += 32){
    const int kb = kbase + k0;
    const float4* Ap = (const float4*)(A + (size_t)sb * K + kb + sk);
    float4 a0 = Ap[0], a1 = Ap[1], a2 = Ap[2], a3 = Ap[3];
    size_t we = wOff + (size_t)(n0 + wn) * K + kb + wk;
    float w0,w1,w2,w3,w4,w5,w6,w7;
    if (bf){
      uint4 wv = *(const uint4*)((const u16*)W + we);
      w0=b2f(wv.x); w1=b2f(wv.x>>16); w2=b2f(wv.y); w3=b2f(wv.y>>16);
      w4=b2f(wv.z); w5=b2f(wv.z>>16); w6=b2f(wv.w); w7=b2f(wv.w>>16);
    } else {
      const float* Wf = (const float*)W + we;
      float4 p = *(const float4*)Wf, q = *(const float4*)(Wf + 4);
      w0=p.x; w1=p.y; w2=p.z; w3=p.w; w4=q.x; w5=q.y; w6=q.z; w7=q.w;
    }

    As[sk+ 0][sb]=a0.x; As[sk+ 1][sb]=a0.y; As[sk+ 2][sb]=a0.z; As[sk+ 3][sb]=a0.w;
    As[sk+ 4][sb]=a1.x; As[sk+ 5][sb]=a1.y; As[sk+ 6][sb]=a1.z; As[sk+ 7][sb]=a1.w;
    As[sk+ 8][sb]=a2.x; As[sk+ 9][sb]=a2.y; As[sk+10][sb]=a2.z; As[sk+11][sb]=a2.w;
    As[sk+12][sb]=a3.x; As[sk+13][sb]=a3.y; As[sk+14][sb]=a3.z; As[sk+15][sb]=a3.w;
    Wt[wk+0][wn]=w0; Wt[wk+1][wn]=w1; Wt[wk+2][wn]=w2; Wt[wk+3][wn]=w3;
    Wt[wk+4][wn]=w4; Wt[wk+5][wn]=w5; Wt[wk+6][wn]=w6; Wt[wk+7][wn]=w7;
    __syncthreads();

    #pragma unroll
    for (int kk = 0; kk < 32; ++kk){
      float4 wv = *(const float4*)(&Wt[kk][ny]);
      float a[8];
      #pragma unroll
      for (int i = 0; i < 8; ++i) a[i] = As[kk][bx+i];
      #pragma unroll
      for (int i = 0; i < 8; ++i){
        acc[i][0] = fmaf(a[i], wv.x, acc[i][0]);
        acc[i][1] = fmaf(a[i], wv.y, acc[i][1]);
        acc[i][2] = fmaf(a[i], wv.z, acc[i][2]);
        acc[i][3] = fmaf(a[i], wv.w, acc[i][3]);
      }
    }
    __syncthreads();
  }

  float* Pp = P + (size_t)blockIdx.y * B * N;
  #pragma unroll
  for (int j = 0; j < 4; ++j){
    int n = n0 + ny + j;
    #pragma unroll
    for (int i = 0; i < 8; ++i){
      size_t o = (size_t)(bx + i) * N + n;
      if (OUT == 0) Pp[o] = acc[i][j];
      else          Pp[o] += acc[i][j];
    }
  }
}

// ---- epilogue over B*H: sum splits + bias, activation, strided store ----
// ACT 0: C = s     ACT 1: C = tanh(s)     ACT 2: C = C * 2*sigmoid(s)
template<int ACT>
__global__ void ep_gen(const float* __restrict__ P, int S, const void* __restrict__ bias,
                       size_t bOff, float* __restrict__ C, int ostr,
                       const int* __restrict__ flagp){
  int bf = *flagp;
  int t = blockIdx.x * 256 + threadIdx.x;   // B*H
  int b = t >> 10, h = t & (H - 1);
  float s = 0.f;
  for (int i = 0; i < S; ++i) s += P[(size_t)i * B * H + t];
  s += ldf(bias, bOff + h, bf);
  size_t o = (size_t)b * ostr + h;
  if (ACT == 0)      C[o] = s;
  else if (ACT == 1) C[o] = tanhf(s);
  else               C[o] = C[o] * 2.f * sigm(s);
}

// ---- epilogue: sum gate splits + biases -> LSTM pointwise -> h (opt. mog2 scale) ----
__global__ void ep_lstm(const float* __restrict__ P, int S, const void* __restrict__ bih,
                        const void* __restrict__ bhh, const void* __restrict__ cprev,
                        float* __restrict__ hout, float* __restrict__ hf,
                        const void* __restrict__ mog2b, const int* __restrict__ flagp){
  int bf = *flagp;
  int t = blockIdx.x * 256 + threadIdx.x;   // B*H
  int b = t >> 10, h = t & (H - 1);
  size_t base = (size_t)b * 4 * H;
  float gi=0.f, gf=0.f, gg=0.f, go=0.f;
  for (int s = 0; s < S; ++s){
    const float* q = P + (size_t)s * B * 4 * H + base;
    gi += q[h]; gf += q[H + h]; gg += q[2*H + h]; go += q[3*H + h];
  }
  gi += ldf(bih, h, bf)       + ldf(bhh, h, bf);
  gf += ldf(bih, H + h, bf)   + ldf(bhh, H + h, bf);
  gg += ldf(bih, 2*H + h, bf) + ldf(bhh, 2*H + h, bf);
  go += ldf(bih, 3*H + h, bf) + ldf(bhh, 3*H + h, bf);
  float c = cprev ? sigm(gf) * ldf(cprev, t, bf) : 0.f;
  c += sigm(gi) * tanhf(gg);
  float hv = sigm(go) * tanhf(c);
  if (hf) hf[t] = hv;                 // raw hidden to d_out (layer 2)
  if (mog2b){                         // fold layer-2 mogrifier collapse into the store
    hv *= 8.f * sigm(ldf(mog2b, h, bf)) * sigm(ldf(mog2b, 2*H + h, bf))
              * sigm(ldf(mog2b, 4*H + h, bf));
  }
  hout[t] = hv;
}

// ---- flash attention: one block per (b, seq-quarter); enc read ONCE ----
// scores = r . enc[s,b,:], online softmax, ctx accumulated in registers.
// Partials: Pctx[q][b][h], Pml[q][b][{m,l}] -> combined by k_attn_fin.
template<int BF>
__device__ __forceinline__ void attn_body(const float* __restrict__ CAT,
                                          const void* __restrict__ enc,
                                          float* __restrict__ Pctx,
                                          float* __restrict__ Pml)
{
  __shared__ float els[TS][H];      // 32 KB tile of enc rows
  __shared__ float sc[TS];
  const int t = threadIdx.x;
  const int wave = t >> 6, lane = t & 63;
  const int b = blockIdx.x >> 2, q = blockIdx.x & 3;
  const int s0 = q * SQB;

  // per-thread slice of the query row used by the dot phase: 16 floats at lane*16
  const float* rp = CAT + (size_t)b * 2 * H + lane * 16;
  float4 r0 = *(const float4*)rp,       r1 = *(const float4*)(rp + 4),
         r2 = *(const float4*)(rp + 8), r3 = *(const float4*)(rp + 12);

  float m = -3.0e38f, l = 0.f;
  float a0 = 0.f, a1 = 0.f, a2 = 0.f, a3 = 0.f;
  const int h0 = t * 4;

  float4 v[8];   // f32 prefetch regs
  uint4  u[4];   // bf16 prefetch regs

  auto issue = [&](int tile){
    int ss = s0 + tile * TS;
    if (BF == 0){
      #pragma unroll
      for (int i = 0; i < 8; ++i){
        int seg = i * 256 + t;                 // float4 index in tile
        int r = seg >> 8, c = (seg & 255) * 4;
        v[i] = *(const float4*)((const float*)enc + ((size_t)(ss + r) * B + b) * H + c);
      }
    } else {
      #pragma unroll
      for (int i = 0; i < 4; ++i){
        int seg = i * 256 + t;                 // 8-elem chunk index in tile
        int r = seg >> 7, c = (seg & 127) * 8;
        u[i] = *(const uint4*)((const u16*)enc + ((size_t)(ss + r) * B + b) * H + c);
      }
    }
  };
  auto commit = [&](){
    if (BF == 0){
      #pragma unroll
      for (int i = 0; i < 8; ++i) ((float4*)els)[i * 256 + t] = v[i];
    } else {
      #pragma unroll
      for (int i = 0; i < 4; ++i){
        int seg = i * 256 + t;
        float4 lo = {b2f(u[i].x), b2f(u[i].x >> 16), b2f(u[i].y), b2f(u[i].y >> 16)};
        float4 hi = {b2f(u[i].z), b2f(u[i].z >> 16), b2f(u[i].w), b2f(u[i].w >> 16)};
        ((float4*)els)[seg * 2]     = lo;
        ((float4*)els)[seg * 2 + 1] = hi;
      }
    }
  };

  issue(0);
  commit();
  __syncthreads();

  for (int tile = 0; tile < NT; ++tile){
    if (tile + 1 < NT) issue(tile + 1);     // T14: loads in flight across compute

    // dot phase: wave handles rows {wave*2, wave*2+1}
    #pragma unroll
    for (int i = 0; i < 2; ++i){
      int row = wave * 2 + i;
      const float* e = &els[row][lane * 16];
      float4 e0 = *(const float4*)e,       e1 = *(const float4*)(e + 4),
             e2 = *(const float4*)(e + 8), e3 = *(const float4*)(e + 12);
      float d = e0.x*r0.x + e0.y*r0.y + e0.z*r0.z + e0.w*r0.w
              + e1.x*r1.x + e1.y*r1.y + e1.z*r1.z + e1.w*r1.w
              + e2.x*r2.x + e2.y*r2.y + e2.z*r2.z + e2.w*r2.w
              + e3.x*r3.x + e3.y*r3.y + e3.z*r3.z + e3.w*r3.w;
      #pragma unroll
      for (int o = 32; o; o >>= 1) d += __shfl_down(d, o);
      if (lane == 0) sc[row] = d;
    }
    __syncthreads();

    float s0v = sc[0], s1v = sc[1], s2v = sc[2], s3v = sc[3];
    float s4v = sc[4], s5v = sc[5], s6v = sc[6], s7v = sc[7];
    float tm = fmaxf(fmaxf(fmaxf(s0v, s1v), fmaxf(s2v, s3v)),
                     fmaxf(fmaxf(s4v, s5v), fmaxf(s6v, s7v)));
    float nm = fmaxf(m, tm);
    float scale = expf(m - nm);
    float p0 = expf(s0v - nm), p1 = expf(s1v - nm), p2 = expf(s2v - nm), p3 = expf(s3v - nm);
    float p4 = expf(s4v - nm), p5 = expf(s5v - nm), p6 = expf(s6v - nm), p7 = expf(s7v - nm);
    l = l * scale + (p0 + p1 + p2 + p3 + p4 + p5 + p6 + p7);
    m = nm;
    a0 *= scale; a1 *= scale; a2 *= scale; a3 *= scale;
    #pragma unroll
    for (int s = 0; s < TS; ++s){
      float4 e = *(const float4*)(&els[s][h0]);
      float p = (s == 0 ? p0 : s == 1 ? p1 : s == 2 ? p2 : s == 3 ? p3 :
                 s == 4 ? p4 : s == 5 ? p5 : s == 6 ? p6 : p7);
      a0 = fmaf(p, e.x, a0); a1 = fmaf(p, e.y, a1);
      a2 = fmaf(p, e.z, a2); a3 = fmaf(p, e.w, a3);
    }
    __syncthreads();                         // done reading els

    if (tile + 1 < NT){
      commit();
      __syncthreads();
    }
  }

  float4 av = {a0, a1, a2, a3};
  *(float4*)(Pctx + ((size_t)q * B + b) * H + h0) = av;
  if (t == 0){
    Pml[((size_t)q * B + b) * 2]     = m;
    Pml[((size_t)q * B + b) * 2 + 1] = l;
  }
}

__global__ __launch_bounds__(256)
void k_attn(const float* __restrict__ CAT, const void* __restrict__ enc,
            float* __restrict__ Pctx, float* __restrict__ Pml,
            const int* __restrict__ flagp){
  if (*flagp) attn_body<1>(CAT, enc, Pctx, Pml);
  else        attn_body<0>(CAT, enc, Pctx, Pml);
}

// ---- combine NQ flash partials -> CAT[b][H + h] ----
__global__ void k_attn_fin(const float* __restrict__ Pctx, const float* __restrict__ Pml,
                           float* __restrict__ CAT){
  int t = blockIdx.x * 256 + threadIdx.x;   // B*H
  int b = t >> 10, h = t & (H - 1);
  float M = -3.0e38f;
  #pragma unroll
  for (int q = 0; q < NQ; ++q) M = fmaxf(M, Pml[((size_t)q * B + b) * 2]);
  float num = 0.f, den = 0.f;
  #pragma unroll
  for (int q = 0; q < NQ; ++q){
    float mq = Pml[((size_t)q * B + b) * 2];
    float lq = Pml[((size_t)q * B + b) * 2 + 1];
    float w = expf(mq - M);
    num = fmaf(w, Pctx[((size_t)q * B + b) * H + h], num);
    den = fmaf(w, lq, den);
  }
  CAT[(size_t)b * 2 * H + H + h] = num / den;
}

// ---- X (f32, B*H) -> Xb (bf16) ----
__global__ void k_cvtA(const float* __restrict__ X, u16* __restrict__ Xb){
  int t = blockIdx.x * 256 + threadIdx.x;   // B*H/8 threads
  const float4* p = (const float4*)(X + t * 8);
  float4 f0 = p[0], f1 = p[1];
  uint4 o;
  o.x = cvt2(f0.x, f0.y); o.y = cvt2(f0.z, f0.w);
  o.z = cvt2(f1.x, f1.y); o.w = cvt2(f1.z, f1.w);
  *(uint4*)(Xb + t * 8) = o;
}

// ---- out-GEMM via bf16 MFMA: C[128, VOUT] = Xb @ W^T + bias (W f32/bf16 in HBM) ----
__global__ __launch_bounds__(256)
void gemm_out_mfma(const u16* __restrict__ Xb, const void* __restrict__ W,
                   const void* __restrict__ bias, float* __restrict__ Cg,
                   const int* __restrict__ flagp)
{
  const int bf = *flagp;
  __shared__ u16 Ws[64][72];          // [n][k], 144-B row stride (16B-aligned, 2-way banks)
  const int t = threadIdx.x;
  const int n0 = blockIdx.x * 64;
  const int wave = t >> 6, lane = t & 63;
  const int m0 = wave * 32;
  const int lm = lane & 15, quad = lane >> 4;
  const int sn = t >> 2, sk = (t & 3) * 16;   // staging: 64 n-rows x 4 thr x 16 k

  f32x4 acc[2][4];
  #pragma unroll
  for (int i = 0; i < 2; ++i)
    #pragma unroll
    for (int j = 0; j < 4; ++j) acc[i][j] = (f32x4){0.f, 0.f, 0.f, 0.f};

  for (int k0 = 0; k0 < H; k0 += 64){
    if (bf){
      const u16* wp = (const u16*)W + (size_t)(n0 + sn) * H + k0 + sk;
      *(uint4*)(&Ws[sn][sk])     = *(const uint4*)wp;
      *(uint4*)(&Ws[sn][sk + 8]) = *(const uint4*)(wp + 8);
    } else {
      const float* wp = (const float*)W + (size_t)(n0 + sn) * H + k0 + sk;
      float4 f0 = *(const float4*)wp,     f1 = *(const float4*)(wp + 4);
      float4 f2 = *(const float4*)(wp+8), f3 = *(const float4*)(wp + 12);
      uint4 o0, o1;
      o0.x = cvt2(f0.x, f0.y); o0.y = cvt2(f0.z, f0.w);
      o0.z = cvt2(f1.x, f1.y); o0.w = cvt2(f1.z, f1.w);
      o1.x = cvt2(f2.x, f2.y); o1.y = cvt2(f2.z, f2.w);
      o1.z = cvt2(f3.x, f3.y); o1.w = cvt2(f3.z, f3.w);
      *(uint4*)(&Ws[sn][sk])     = o0;
      *(uint4*)(&Ws[sn][sk + 8]) = o1;
    }
    __syncthreads();
    #pragma unroll
    for (int ks = 0; ks < 64; ks += 32){
      bf16x8 a0 = *(const bf16x8*)(Xb + (size_t)(m0 + lm) * H + k0 + ks + quad * 8);
      bf16x8 a1 = *(const bf16x8*)(Xb + (size_t)(m0 + 16 + lm) * H + k0 + ks + quad * 8);
      #pragma unroll
      for (int nt = 0; nt < 4; ++nt){
        bf16x8 bfr = *(const bf16x8*)(&Ws[nt * 16 + lm][ks + quad * 8]);
        acc[0][nt] = __builtin_amdgcn_mfma_f32_16x16x32_bf16(a0, bfr, acc[0][nt], 0, 0, 0);
        acc[1][nt] = __builtin_amdgcn_mfma_f32_16x16x32_bf16(a1, bfr, acc[1][nt], 0, 0, 0);
      }
    }
    __syncthreads();
  }

  #pragma unroll
  for (int nt = 0; nt < 4; ++nt){
    int n = n0 + nt * 16 + lm;
    float bj = ldf(bias, n, bf);
    #pragma unroll
    for (int mt = 0; mt < 2; ++mt)
      #pragma unroll
      for (int r = 0; r < 4; ++r){
        int m = m0 + mt * 16 + quad * 4 + r;
        Cg[(size_t)m * VOUT + n] = acc[mt][nt][r] + bj;
      }
  }
}

// ---- softmax over VOUT, f32 in-place in d_out, one block (1024 thr) per b ----
__global__ __launch_bounds__(1024)
void k_softmax_v(float* __restrict__ out){
  int b = blockIdx.x, t = threadIdx.x;
  float* row = out + (size_t)b * VOUT;
  __shared__ float rm[16], rs[16];
  int lane = t & 63, w = t >> 6;
  float m = -3.0e38f;
  for (int i = 4*t; i < VOUT; i += 4096){
    float4 v = *(const float4*)(row + i);
    m = fmaxf(m, fmaxf(fmaxf(v.x, v.y), fmaxf(v.z, v.w)));
  }
  #pragma unroll
  for (int o = 32; o; o >>= 1) m = fmaxf(m, __shfl_down(m, o));
  if (!lane) rm[w] = m;
  __syncthreads();
  float M = rm[0];
  #pragma unroll
  for (int i = 1; i < 16; ++i) M = fmaxf(M, rm[i]);
  float s = 0.f;
  for (int i = 4*t; i < VOUT; i += 4096){
    float4 v = *(const float4*)(row + i);
    s += expf(v.x-M) + expf(v.y-M) + expf(v.z-M) + expf(v.w-M);
  }
  #pragma unroll
  for (int o = 32; o; o >>= 1) s += __shfl_down(s, o);
  if (!lane) rs[w] = s;
  __syncthreads();
  float S = rs[0];
  #pragma unroll
  for (int i = 1; i < 16; ++i) S += rs[i];
  float inv = 1.f / S;
  for (int i = 4*t; i < VOUT; i += 4096){
    float4 v = *(const float4*)(row + i);
    v.x = expf(v.x-M)*inv; v.y = expf(v.y-M)*inv;
    v.z = expf(v.z-M)*inv; v.w = expf(v.w-M)*inv;
    *(float4*)(row + i) = v;
  }
}

extern "C" void kernel_launch(void* const* d_in, const int* in_sizes, int n_in,
                              void* d_out, int out_size, void* d_ws, size_t ws_size,
                              hipStream_t stream){
  (void)in_sizes; (void)n_in; (void)out_size;
  const int* idx   = (const int*)d_in[0];
  const void* enc  = d_in[1];
  const void* h1   = d_in[2];
  const void* c1   = d_in[3];
  const void* emb  = d_in[4];
  const void* mog1W= d_in[5];
  const void* mog1b= d_in[6];
  const void* Wih1 = d_in[7];
  const void* Whh1 = d_in[8];
  const void* bih1 = d_in[9];
  const void* bhh1 = d_in[10];
  // d_in[11] mog2_W: dead (layer-2 mogrifier h stays 0)
  const void* mog2b= d_in[12];
  const void* Wih2 = d_in[13];
  // d_in[14] lstm2_Whh: dead (h=0)
  const void* bih2 = d_in[15];
  const void* bhh2 = d_in[16];
  const void* fcW  = d_in[17];
  const void* fcb  = d_in[18];
  const void* ccW  = d_in[19];
  const void* ccb  = d_in[20];
  const void* outW = d_in[21];
  const void* outb = d_in[22];

  float* X    = (float*)d_ws;         // B*H  (x / h1n-scaled / concat_out)
  float* Hb   = X   + B*H;            // B*H  (h)
  float* H2   = Hb  + B*H;            // B*H  (h2)
  float* CAT  = H2  + B*H;            // B*2H (rnn_out | context)
  float* SC   = CAT + (size_t)B*2*H;  // B*SEQ (unused now; layout kept)
  int*  FLAG  = (int*)(SC + B*SEQ);   // 64 ints
  u16*  Xb    = (u16*)(FLAG + 64);    // B*H bf16
  float* P    = (float*)(Xb + B*H);   // split-K partials (16*B*H f32 max) / attn partials

  size_t need = ((size_t)(5*B*H + B*SEQ) + 64) * 4 + (size_t)B*H*2 + (size_t)4*B*4*H*4;
  int S1 = 16, S2 = 4;
  if (ws_size < need) { S1 = 4; S2 = 1; }

  float* out_f = (float*)d_out;               // [B, VOUT] probs
  float* hid_f = out_f + (size_t)B * VOUT;    // [1, B, H] hidden

  k_detect<<<1, 256, 0, stream>>>((const u16*)enc, FLAG);
  k_init<<<B*H/256, 256, 0, stream>>>(idx, emb, h1, X, Hb, FLAG);

  // layer-1 mogrifier: i even -> x = 2sig(h@W^T+b)*x ; i odd -> h = 2sig(x@W^T+b)*h
  for (int i = 0; i < 5; ++i){
    const float* a = (i & 1) ? X : Hb;
    float*       c = (i & 1) ? Hb : X;
    gemm_s<0><<<dim3(H/64, S1), 256, 0, stream>>>(a, mog1W, (size_t)i*H*H, P, H, H/S1, H, FLAG);
    ep_gen<2><<<B*H/256, 256, 0, stream>>>(P, S1, mog1b, (size_t)i*H, c, H, FLAG);
  }

  // layer-1 LSTM gates -> h1n (scaled by layer-2 mogrifier collapse) into X
  gemm_s<0><<<dim3(4*H/64, S2), 256, 0, stream>>>(X,  Wih1, 0, P, H, H/S2, 4*H, FLAG);
  gemm_s<1><<<dim3(4*H/64, S2), 256, 0, stream>>>(Hb, Whh1, 0, P, H, H/S2, 4*H, FLAG);
  ep_lstm<<<B*H/256, 256, 0, stream>>>(P, S2, bih1, bhh1, c1, X, nullptr, mog2b, FLAG);

  // layer-2 LSTM (h=c=0) -> H2 + f32 hidden out
  gemm_s<0><<<dim3(4*H/64, S2), 256, 0, stream>>>(X, Wih2, 0, P, H, H/S2, 4*H, FLAG);
  ep_lstm<<<B*H/256, 256, 0, stream>>>(P, S2, bih2, bhh2, nullptr, H2, hid_f, nullptr, FLAG);

  // fc -> rnn_out straight into CAT[:, 0:H]
  gemm_s<0><<<dim3(H/64, S1), 256, 0, stream>>>(H2, fcW, 0, P, H, H/S1, H, FLAG);
  ep_gen<0><<<B*H/256, 256, 0, stream>>>(P, S1, fcb, 0, CAT, 2*H, FLAG);

  // flash attention: enc read once; 4 seq-partials combined into CAT[:, H:2H]
  float* Pctx = P;                      // NQ*B*H floats (2 MB)
  float* Pml  = P + (size_t)NQ*B*H;     // NQ*B*2 floats
  k_attn<<<B*NQ, 256, 0, stream>>>(CAT, enc, Pctx, Pml, FLAG);
  k_attn_fin<<<B*H/256, 256, 0, stream>>>(Pctx, Pml, CAT);

  // concat fc (K=2H) -> X ; MFMA out logits -> d_out ; vocab softmax
  gemm_s<0><<<dim3(H/64, S1), 256, 0, stream>>>(CAT, ccW, 0, P, 2*H, 2*H/S1, H, FLAG);
  ep_gen<1><<<B*H/256, 256, 0, stream>>>(P, S1, ccb, 0, X, H, FLAG);
  k_cvtA<<<B*H/(256*8), 256, 0, stream>>>(X, Xb);
  gemm_out_mfma<<<VOUT/64, 256, 0, stream>>>(Xb, outW, outb, out_f, FLAG);
  k_softmax_v<<<B, 1024, 0, stream>>>(out_f);
}

// Round 2
// 802.696 us; speedup vs baseline: 1.2136x; 1.1157x over previous
//
#include <hip/hip_runtime.h>
#include <math.h>

typedef unsigned short u16;
typedef unsigned int   u32;

#define B    128
#define H    1024
#define SEQ  512
#define VOUT 32000

#define NQ   4            // seq splits for flash attention
#define SQB  (SEQ / NQ)   // 128 seq positions per block
#define TS   8            // tile of seq rows staged in LDS
#define NT   (SQB / TS)   // 16 tiles per block

using bf16x8 = __attribute__((ext_vector_type(8))) short;
using f32x4  = __attribute__((ext_vector_type(4))) float;

__device__ __forceinline__ float b2f(u32 u){ return __uint_as_float((u & 0xffffu) << 16); }
__device__ __forceinline__ float sigm(float x){ return 1.0f / (1.0f + expf(-x)); }
__device__ __forceinline__ u32 cvt2(float a, float b){   // pack bf16(a) lo | bf16(b) hi, RNE
  u32 ua = __float_as_uint(a); ua += 0x7fffu + ((ua >> 16) & 1u);
  u32 ub = __float_as_uint(b); ub += 0x7fffu + ((ub >> 16) & 1u);
  return (ua >> 16) | (ub & 0xffff0000u);
}
__device__ __forceinline__ u16 f2b(float x){   // RNE f32 -> bf16
  u32 u = __float_as_uint(x); u += 0x7fffu + ((u >> 16) & 1u); return (u16)(u >> 16);
}
__device__ __forceinline__ float bval(u16 h){ return __uint_as_float((u32)h << 16); }
// split f32 pair into packed bf16 hi + bf16 lo (residual) words
__device__ __forceinline__ void split2(float a, float b, u32& hp, u32& lp){
  u16 ha = f2b(a), hb = f2b(b);
  u16 la = f2b(a - bval(ha)), lb = f2b(b - bval(hb));
  hp = (u32)ha | ((u32)hb << 16);
  lp = (u32)la | ((u32)lb << 16);
}

// generic element load: bf=1 -> data is bf16 (u16); bf=0 -> data is f32
__device__ __forceinline__ float ldf(const void* p, size_t i, int bf){
  return bf ? b2f(((const u16*)p)[i]) : ((const float*)p)[i];
}

// ---- runtime input-dtype detection (1 = bf16, 0 = f32); proven: picks f32 here ----
__global__ void k_detect(const u16* __restrict__ enc, int* __restrict__ flag){
  __shared__ int cnt;
  if (threadIdx.x == 0) cnt = 0;
  __syncthreads();
  int c = 0;
  for (int j = threadIdx.x; j < 512; j += 256){
    u32 u = enc[j];
    u32 e = (u >> 7) & 0xFFu;
    c += (u == 0u || (e >= 100u && e <= 130u)) ? 1 : 0;
  }
  atomicAdd(&cnt, c);
  __syncthreads();
  if (threadIdx.x == 0) *flag = (cnt > 410) ? 1 : 0;
}

// ---- init: X = emb[idx], Hb = h1 (f32) + their bf16 hi/lo splits ----
__global__ void k_init(const int* __restrict__ idx, const void* __restrict__ emb,
                       const void* __restrict__ h1, float* __restrict__ X, float* __restrict__ Hb,
                       u16* __restrict__ SAh, u16* __restrict__ SAl,
                       u16* __restrict__ SBh, u16* __restrict__ SBl,
                       const int* __restrict__ flagp){
  int bf = *flagp;
  int t = blockIdx.x * 256 + threadIdx.x;   // B*H threads
  int b = t >> 10, h = t & (H - 1);
  float xv = ldf(emb, (size_t)idx[b] * H + h, bf);
  float hv = ldf(h1, t, bf);
  X[t]  = xv; Hb[t] = hv;
  u16 xh = f2b(xv); SAh[t] = xh; SAl[t] = f2b(xv - bval(xh));
  u16 hh = f2b(hv); SBh[t] = hh; SBl[t] = f2b(hv - bval(hh));
}

// ---- 3-pass split-bf16 MFMA GEMM ----
// P[split][m][n] = sum_op A_op[m, kslice] @ W_op[n, kslice]^T
// A as bf16 hi/lo arrays [B][K]; W f32 or bf16 [N][K] in HBM (wOff elems, W0 only).
// grid = (N/64, SPLITS); 256 thr = 4 waves; wave owns 32 m-rows; Kc multiple of 64.
template<int NOPS>
__global__ __launch_bounds__(256)
void gemm3(const u16* __restrict__ A0h, const u16* __restrict__ A0l,
           const u16* __restrict__ A1h, const u16* __restrict__ A1l,
           const void* __restrict__ W0, const void* __restrict__ W1, size_t wOff,
           float* __restrict__ P, int K, int Kc, int N, const int* __restrict__ flagp)
{
  const int bf = *flagp;
  __shared__ u16 Wh[64][72];          // [n][k] hi, 144-B row stride (16B aligned)
  __shared__ u16 Wl[64][72];          // [n][k] lo
  const int t = threadIdx.x;
  const int n0 = blockIdx.x * 64;
  const int kbase = blockIdx.y * Kc;
  const int wave = t >> 6, lane = t & 63;
  const int m0 = wave * 32;
  const int lm = lane & 15, quad = lane >> 4;
  const int sn = t >> 2, sk = (t & 3) * 16;   // staging: 64 n-rows x 4 thr x 16 k

  f32x4 acc[2][4];
  #pragma unroll
  for (int i = 0; i < 2; ++i)
    #pragma unroll
    for (int j = 0; j < 4; ++j) acc[i][j] = (f32x4){0.f, 0.f, 0.f, 0.f};

  #pragma unroll
  for (int op = 0; op < NOPS; ++op){
    const u16* Ah = (NOPS == 2 && op) ? A1h : A0h;
    const u16* Al = (NOPS == 2 && op) ? A1l : A0l;
    const void* W = (NOPS == 2 && op) ? W1  : W0;
    for (int k0 = kbase; k0 < kbase + Kc; k0 += 64){
      if (bf){
        const u16* wp = (const u16*)W + wOff + (size_t)(n0 + sn) * K + k0 + sk;
        *(uint4*)(&Wh[sn][sk])     = *(const uint4*)wp;
        *(uint4*)(&Wh[sn][sk + 8]) = *(const uint4*)(wp + 8);
        uint4 z = {0u, 0u, 0u, 0u};
        *(uint4*)(&Wl[sn][sk])     = z;
        *(uint4*)(&Wl[sn][sk + 8]) = z;
      } else {
        const float* wp = (const float*)W + wOff + (size_t)(n0 + sn) * K + k0 + sk;
        float4 f0 = *(const float4*)wp,       f1 = *(const float4*)(wp + 4);
        float4 f2 = *(const float4*)(wp + 8), f3 = *(const float4*)(wp + 12);
        uint4 hi0, lo0, hi1, lo1;
        split2(f0.x, f0.y, hi0.x, lo0.x); split2(f0.z, f0.w, hi0.y, lo0.y);
        split2(f1.x, f1.y, hi0.z, lo0.z); split2(f1.z, f1.w, hi0.w, lo0.w);
        split2(f2.x, f2.y, hi1.x, lo1.x); split2(f2.z, f2.w, hi1.y, lo1.y);
        split2(f3.x, f3.y, hi1.z, lo1.z); split2(f3.z, f3.w, hi1.w, lo1.w);
        *(uint4*)(&Wh[sn][sk])     = hi0;
        *(uint4*)(&Wh[sn][sk + 8]) = hi1;
        *(uint4*)(&Wl[sn][sk])     = lo0;
        *(uint4*)(&Wl[sn][sk + 8]) = lo1;
      }
      __syncthreads();
      #pragma unroll
      for (int ks = 0; ks < 64; ks += 32){
        size_t ab = (size_t)(m0 + lm) * K + k0 + ks + quad * 8;
        bf16x8 ah0 = *(const bf16x8*)(Ah + ab);
        bf16x8 al0 = *(const bf16x8*)(Al + ab);
        bf16x8 ah1 = *(const bf16x8*)(Ah + ab + (size_t)16 * K);
        bf16x8 al1 = *(const bf16x8*)(Al + ab + (size_t)16 * K);
        #pragma unroll
        for (int nt = 0; nt < 4; ++nt){
          bf16x8 bh = *(const bf16x8*)(&Wh[nt * 16 + lm][ks + quad * 8]);
          acc[0][nt] = __builtin_amdgcn_mfma_f32_16x16x32_bf16(ah0, bh, acc[0][nt], 0, 0, 0);
          acc[1][nt] = __builtin_amdgcn_mfma_f32_16x16x32_bf16(ah1, bh, acc[1][nt], 0, 0, 0);
          acc[0][nt] = __builtin_amdgcn_mfma_f32_16x16x32_bf16(al0, bh, acc[0][nt], 0, 0, 0);
          acc[1][nt] = __builtin_amdgcn_mfma_f32_16x16x32_bf16(al1, bh, acc[1][nt], 0, 0, 0);
          if (!bf){
            bf16x8 bl = *(const bf16x8*)(&Wl[nt * 16 + lm][ks + quad * 8]);
            acc[0][nt] = __builtin_amdgcn_mfma_f32_16x16x32_bf16(ah0, bl, acc[0][nt], 0, 0, 0);
            acc[1][nt] = __builtin_amdgcn_mfma_f32_16x16x32_bf16(ah1, bl, acc[1][nt], 0, 0, 0);
          }
        }
      }
      __syncthreads();
    }
  }

  float* Pp = P + (size_t)blockIdx.y * B * N;
  #pragma unroll
  for (int nt = 0; nt < 4; ++nt){
    int n = n0 + nt * 16 + lm;
    #pragma unroll
    for (int mt = 0; mt < 2; ++mt)
      #pragma unroll
      for (int r = 0; r < 4; ++r){
        int m = m0 + mt * 16 + quad * 4 + r;
        Pp[(size_t)m * N + n] = acc[mt][nt][r];
      }
  }
}

// ---- split-K GEMM (f32 VALU; kept for concat K=2H) ----
template<int OUT>
__global__ __launch_bounds__(256)
void gemm_s(const float* __restrict__ A, const void* __restrict__ W, size_t wOff,
            float* __restrict__ P, int K, int Kc, int N, const int* __restrict__ flagp)
{
  const int bf = *flagp;
  __shared__ float As[32][132];   // [k][b], padded
  __shared__ float Wt[32][68];    // [k][n], padded
  const int t  = threadIdx.x;
  const int n0 = blockIdx.x * 64;
  const int kbase = blockIdx.y * Kc;
  const int sb = t >> 1,  sk = (t & 1) << 4;
  const int wn = t >> 2,  wk = (t & 3) << 3;
  const int bx = (t & 15) << 3;
  const int ny = (t >> 4) << 2;

  float acc[8][4];
  #pragma unroll
  for (int i = 0; i < 8; ++i)
    #pragma unroll
    for (int j = 0; j < 4; ++j) acc[i][j] = 0.f;

  for (int k0 = 0; k0 < Kc; k0 += 32){
    const int kb = kbase + k0;
    const float4* Ap = (const float4*)(A + (size_t)sb * K + kb + sk);
    float4 a0 = Ap[0], a1 = Ap[1], a2 = Ap[2], a3 = Ap[3];
    size_t we = wOff + (size_t)(n0 + wn) * K + kb + wk;
    float w0,w1,w2,w3,w4,w5,w6,w7;
    if (bf){
      uint4 wv = *(const uint4*)((const u16*)W + we);
      w0=b2f(wv.x); w1=b2f(wv.x>>16); w2=b2f(wv.y); w3=b2f(wv.y>>16);
      w4=b2f(wv.z); w5=b2f(wv.z>>16); w6=b2f(wv.w); w7=b2f(wv.w>>16);
    } else {
      const float* Wf = (const float*)W + we;
      float4 p = *(const float4*)Wf, q = *(const float4*)(Wf + 4);
      w0=p.x; w1=p.y; w2=p.z; w3=p.w; w4=q.x; w5=q.y; w6=q.z; w7=q.w;
    }

    As[sk+ 0][sb]=a0.x; As[sk+ 1][sb]=a0.y; As[sk+ 2][sb]=a0.z; As[sk+ 3][sb]=a0.w;
    As[sk+ 4][sb]=a1.x; As[sk+ 5][sb]=a1.y; As[sk+ 6][sb]=a1.z; As[sk+ 7][sb]=a1.w;
    As[sk+ 8][sb]=a2.x; As[sk+ 9][sb]=a2.y; As[sk+10][sb]=a2.z; As[sk+11][sb]=a2.w;
    As[sk+12][sb]=a3.x; As[sk+13][sb]=a3.y; As[sk+14][sb]=a3.z; As[sk+15][sb]=a3.w;
    Wt[wk+0][wn]=w0; Wt[wk+1][wn]=w1; Wt[wk+2][wn]=w2; Wt[wk+3][wn]=w3;
    Wt[wk+4][wn]=w4; Wt[wk+5][wn]=w5; Wt[wk+6][wn]=w6; Wt[wk+7][wn]=w7;
    __syncthreads();

    #pragma unroll
    for (int kk = 0; kk < 32; ++kk){
      float4 wv = *(const float4*)(&Wt[kk][ny]);
      float a[8];
      #pragma unroll
      for (int i = 0; i < 8; ++i) a[i] = As[kk][bx+i];
      #pragma unroll
      for (int i = 0; i < 8; ++i){
        acc[i][0] = fmaf(a[i], wv.x, acc[i][0]);
        acc[i][1] = fmaf(a[i], wv.y, acc[i][1]);
        acc[i][2] = fmaf(a[i], wv.z, acc[i][2]);
        acc[i][3] = fmaf(a[i], wv.w, acc[i][3]);
      }
    }
    __syncthreads();
  }

  float* Pp = P + (size_t)blockIdx.y * B * N;
  #pragma unroll
  for (int j = 0; j < 4; ++j){
    int n = n0 + ny + j;
    #pragma unroll
    for (int i = 0; i < 8; ++i){
      size_t o = (size_t)(bx + i) * N + n;
      if (OUT == 0) Pp[o] = acc[i][j];
      else          Pp[o] += acc[i][j];
    }
  }
}

// ---- epilogue over B*H: sum splits + bias, activation, strided store ----
// ACT 0: C = s     ACT 1: C = tanh(s)     ACT 2: C = C * 2*sigmoid(s)
// sh/sl (optional): bf16 hi / lo split of stored value at flat index t
template<int ACT>
__global__ void ep_gen(const float* __restrict__ P, int S, const void* __restrict__ bias,
                       size_t bOff, float* __restrict__ C, int ostr,
                       u16* __restrict__ sh, u16* __restrict__ sl,
                       const int* __restrict__ flagp){
  int bf = *flagp;
  int t = blockIdx.x * 256 + threadIdx.x;   // B*H
  int b = t >> 10, h = t & (H - 1);
  float s = 0.f;
  for (int i = 0; i < S; ++i) s += P[(size_t)i * B * H + t];
  s += ldf(bias, bOff + h, bf);
  size_t o = (size_t)b * ostr + h;
  float v;
  if (ACT == 0)      v = s;
  else if (ACT == 1) v = tanhf(s);
  else               v = C[o] * 2.f * sigm(s);
  C[o] = v;
  if (sh){ u16 hv = f2b(v); sh[t] = hv; if (sl) sl[t] = f2b(v - bval(hv)); }
}

// ---- epilogue: sum gate splits + biases -> LSTM pointwise -> h (opt. mog2 scale) ----
__global__ void ep_lstm(const float* __restrict__ P, int S, const void* __restrict__ bih,
                        const void* __restrict__ bhh, const void* __restrict__ cprev,
                        float* __restrict__ hout, float* __restrict__ hf,
                        const void* __restrict__ mog2b,
                        u16* __restrict__ sh, u16* __restrict__ sl,
                        const int* __restrict__ flagp){
  int bf = *flagp;
  int t = blockIdx.x * 256 + threadIdx.x;   // B*H
  int b = t >> 10, h = t & (H - 1);
  size_t base = (size_t)b * 4 * H;
  float gi=0.f, gf=0.f, gg=0.f, go=0.f;
  for (int s = 0; s < S; ++s){
    const float* q = P + (size_t)s * B * 4 * H + base;
    gi += q[h]; gf += q[H + h]; gg += q[2*H + h]; go += q[3*H + h];
  }
  gi += ldf(bih, h, bf)       + ldf(bhh, h, bf);
  gf += ldf(bih, H + h, bf)   + ldf(bhh, H + h, bf);
  gg += ldf(bih, 2*H + h, bf) + ldf(bhh, 2*H + h, bf);
  go += ldf(bih, 3*H + h, bf) + ldf(bhh, 3*H + h, bf);
  float c = cprev ? sigm(gf) * ldf(cprev, t, bf) : 0.f;
  c += sigm(gi) * tanhf(gg);
  float hv = sigm(go) * tanhf(c);
  if (hf) hf[t] = hv;                 // raw hidden to d_out (layer 2)
  if (mog2b){                         // fold layer-2 mogrifier collapse into the store
    hv *= 8.f * sigm(ldf(mog2b, h, bf)) * sigm(ldf(mog2b, 2*H + h, bf))
              * sigm(ldf(mog2b, 4*H + h, bf));
  }
  hout[t] = hv;
  if (sh){ u16 hb16 = f2b(hv); sh[t] = hb16; sl[t] = f2b(hv - bval(hb16)); }
}

// ---- flash attention: one block per (b, seq-quarter); enc read ONCE ----
template<int BF>
__device__ __forceinline__ void attn_body(const float* __restrict__ CAT,
                                          const void* __restrict__ enc,
                                          float* __restrict__ Pctx,
                                          float* __restrict__ Pml)
{
  __shared__ float els[TS][H];      // 32 KB tile of enc rows
  __shared__ float sc[TS];
  const int t = threadIdx.x;
  const int wave = t >> 6, lane = t & 63;
  const int b = blockIdx.x >> 2, q = blockIdx.x & 3;
  const int s0 = q * SQB;

  const float* rp = CAT + (size_t)b * 2 * H + lane * 16;
  float4 r0 = *(const float4*)rp,       r1 = *(const float4*)(rp + 4),
         r2 = *(const float4*)(rp + 8), r3 = *(const float4*)(rp + 12);

  float m = -3.0e38f, l = 0.f;
  float a0 = 0.f, a1 = 0.f, a2 = 0.f, a3 = 0.f;
  const int h0 = t * 4;

  float4 v[8];   // f32 prefetch regs
  uint4  u[4];   // bf16 prefetch regs

  auto issue = [&](int tile){
    int ss = s0 + tile * TS;
    if (BF == 0){
      #pragma unroll
      for (int i = 0; i < 8; ++i){
        int seg = i * 256 + t;
        int r = seg >> 8, c = (seg & 255) * 4;
        v[i] = *(const float4*)((const float*)enc + ((size_t)(ss + r) * B + b) * H + c);
      }
    } else {
      #pragma unroll
      for (int i = 0; i < 4; ++i){
        int seg = i * 256 + t;
        int r = seg >> 7, c = (seg & 127) * 8;
        u[i] = *(const uint4*)((const u16*)enc + ((size_t)(ss + r) * B + b) * H + c);
      }
    }
  };
  auto commit = [&](){
    if (BF == 0){
      #pragma unroll
      for (int i = 0; i < 8; ++i) ((float4*)els)[i * 256 + t] = v[i];
    } else {
      #pragma unroll
      for (int i = 0; i < 4; ++i){
        int seg = i * 256 + t;
        float4 lo = {b2f(u[i].x), b2f(u[i].x >> 16), b2f(u[i].y), b2f(u[i].y >> 16)};
        float4 hi = {b2f(u[i].z), b2f(u[i].z >> 16), b2f(u[i].w), b2f(u[i].w >> 16)};
        ((float4*)els)[seg * 2]     = lo;
        ((float4*)els)[seg * 2 + 1] = hi;
      }
    }
  };

  issue(0);
  commit();
  __syncthreads();

  for (int tile = 0; tile < NT; ++tile){
    if (tile + 1 < NT) issue(tile + 1);

    #pragma unroll
    for (int i = 0; i < 2; ++i){
      int row = wave * 2 + i;
      const float* e = &els[row][lane * 16];
      float4 e0 = *(const float4*)e,       e1 = *(const float4*)(e + 4),
             e2 = *(const float4*)(e + 8), e3 = *(const float4*)(e + 12);
      float d = e0.x*r0.x + e0.y*r0.y + e0.z*r0.z + e0.w*r0.w
              + e1.x*r1.x + e1.y*r1.y + e1.z*r1.z + e1.w*r1.w
              + e2.x*r2.x + e2.y*r2.y + e2.z*r2.z + e2.w*r2.w
              + e3.x*r3.x + e3.y*r3.y + e3.z*r3.z + e3.w*r3.w;
      #pragma unroll
      for (int o = 32; o; o >>= 1) d += __shfl_down(d, o);
      if (lane == 0) sc[row] = d;
    }
    __syncthreads();

    float s0v = sc[0], s1v = sc[1], s2v = sc[2], s3v = sc[3];
    float s4v = sc[4], s5v = sc[5], s6v = sc[6], s7v = sc[7];
    float tm = fmaxf(fmaxf(fmaxf(s0v, s1v), fmaxf(s2v, s3v)),
                     fmaxf(fmaxf(s4v, s5v), fmaxf(s6v, s7v)));
    float nm = fmaxf(m, tm);
    float scale = expf(m - nm);
    float p0 = expf(s0v - nm), p1 = expf(s1v - nm), p2 = expf(s2v - nm), p3 = expf(s3v - nm);
    float p4 = expf(s4v - nm), p5 = expf(s5v - nm), p6 = expf(s6v - nm), p7 = expf(s7v - nm);
    l = l * scale + (p0 + p1 + p2 + p3 + p4 + p5 + p6 + p7);
    m = nm;
    a0 *= scale; a1 *= scale; a2 *= scale; a3 *= scale;
    #pragma unroll
    for (int s = 0; s < TS; ++s){
      float4 e = *(const float4*)(&els[s][h0]);
      float p = (s == 0 ? p0 : s == 1 ? p1 : s == 2 ? p2 : s == 3 ? p3 :
                 s == 4 ? p4 : s == 5 ? p5 : s == 6 ? p6 : p7);
      a0 = fmaf(p, e.x, a0); a1 = fmaf(p, e.y, a1);
      a2 = fmaf(p, e.z, a2); a3 = fmaf(p, e.w, a3);
    }
    __syncthreads();

    if (tile + 1 < NT){
      commit();
      __syncthreads();
    }
  }

  float4 av = {a0, a1, a2, a3};
  *(float4*)(Pctx + ((size_t)q * B + b) * H + h0) = av;
  if (t == 0){
    Pml[((size_t)q * B + b) * 2]     = m;
    Pml[((size_t)q * B + b) * 2 + 1] = l;
  }
}

__global__ __launch_bounds__(256)
void k_attn(const float* __restrict__ CAT, const void* __restrict__ enc,
            float* __restrict__ Pctx, float* __restrict__ Pml,
            const int* __restrict__ flagp){
  if (*flagp) attn_body<1>(CAT, enc, Pctx, Pml);
  else        attn_body<0>(CAT, enc, Pctx, Pml);
}

// ---- combine NQ flash partials -> CAT[b][H + h] ----
__global__ void k_attn_fin(const float* __restrict__ Pctx, const float* __restrict__ Pml,
                           float* __restrict__ CAT){
  int t = blockIdx.x * 256 + threadIdx.x;   // B*H
  int b = t >> 10, h = t & (H - 1);
  float M = -3.0e38f;
  #pragma unroll
  for (int q = 0; q < NQ; ++q) M = fmaxf(M, Pml[((size_t)q * B + b) * 2]);
  float num = 0.f, den = 0.f;
  #pragma unroll
  for (int q = 0; q < NQ; ++q){
    float mq = Pml[((size_t)q * B + b) * 2];
    float lq = Pml[((size_t)q * B + b) * 2 + 1];
    float w = expf(mq - M);
    num = fmaf(w, Pctx[((size_t)q * B + b) * H + h], num);
    den = fmaf(w, lq, den);
  }
  CAT[(size_t)b * 2 * H + H + h] = num / den;
}

// ---- out-GEMM via bf16 MFMA: C[128, VOUT] = Xb @ W^T + bias (W f32/bf16 in HBM) ----
__global__ __launch_bounds__(256)
void gemm_out_mfma(const u16* __restrict__ Xb, const void* __restrict__ W,
                   const void* __restrict__ bias, float* __restrict__ Cg,
                   const int* __restrict__ flagp)
{
  const int bf = *flagp;
  __shared__ u16 Ws[64][72];          // [n][k], 144-B row stride
  const int t = threadIdx.x;
  const int n0 = blockIdx.x * 64;
  const int wave = t >> 6, lane = t & 63;
  const int m0 = wave * 32;
  const int lm = lane & 15, quad = lane >> 4;
  const int sn = t >> 2, sk = (t & 3) * 16;

  f32x4 acc[2][4];
  #pragma unroll
  for (int i = 0; i < 2; ++i)
    #pragma unroll
    for (int j = 0; j < 4; ++j) acc[i][j] = (f32x4){0.f, 0.f, 0.f, 0.f};

  for (int k0 = 0; k0 < H; k0 += 64){
    if (bf){
      const u16* wp = (const u16*)W + (size_t)(n0 + sn) * H + k0 + sk;
      *(uint4*)(&Ws[sn][sk])     = *(const uint4*)wp;
      *(uint4*)(&Ws[sn][sk + 8]) = *(const uint4*)(wp + 8);
    } else {
      const float* wp = (const float*)W + (size_t)(n0 + sn) * H + k0 + sk;
      float4 f0 = *(const float4*)wp,     f1 = *(const float4*)(wp + 4);
      float4 f2 = *(const float4*)(wp+8), f3 = *(const float4*)(wp + 12);
      uint4 o0, o1;
      o0.x = cvt2(f0.x, f0.y); o0.y = cvt2(f0.z, f0.w);
      o0.z = cvt2(f1.x, f1.y); o0.w = cvt2(f1.z, f1.w);
      o1.x = cvt2(f2.x, f2.y); o1.y = cvt2(f2.z, f2.w);
      o1.z = cvt2(f3.x, f3.y); o1.w = cvt2(f3.z, f3.w);
      *(uint4*)(&Ws[sn][sk])     = o0;
      *(uint4*)(&Ws[sn][sk + 8]) = o1;
    }
    __syncthreads();
    #pragma unroll
    for (int ks = 0; ks < 64; ks += 32){
      bf16x8 a0 = *(const bf16x8*)(Xb + (size_t)(m0 + lm) * H + k0 + ks + quad * 8);
      bf16x8 a1 = *(const bf16x8*)(Xb + (size_t)(m0 + 16 + lm) * H + k0 + ks + quad * 8);
      #pragma unroll
      for (int nt = 0; nt < 4; ++nt){
        bf16x8 bfr = *(const bf16x8*)(&Ws[nt * 16 + lm][ks + quad * 8]);
        acc[0][nt] = __builtin_amdgcn_mfma_f32_16x16x32_bf16(a0, bfr, acc[0][nt], 0, 0, 0);
        acc[1][nt] = __builtin_amdgcn_mfma_f32_16x16x32_bf16(a1, bfr, acc[1][nt], 0, 0, 0);
      }
    }
    __syncthreads();
  }

  #pragma unroll
  for (int nt = 0; nt < 4; ++nt){
    int n = n0 + nt * 16 + lm;
    float bj = ldf(bias, n, bf);
    #pragma unroll
    for (int mt = 0; mt < 2; ++mt)
      #pragma unroll
      for (int r = 0; r < 4; ++r){
        int m = m0 + mt * 16 + quad * 4 + r;
        Cg[(size_t)m * VOUT + n] = acc[mt][nt][r] + bj;
      }
  }
}

// ---- softmax over VOUT, f32 in-place in d_out, one block (1024 thr) per b ----
__global__ __launch_bounds__(1024)
void k_softmax_v(float* __restrict__ out){
  int b = blockIdx.x, t = threadIdx.x;
  float* row = out + (size_t)b * VOUT;
  __shared__ float rm[16], rs[16];
  int lane = t & 63, w = t >> 6;
  float m = -3.0e38f;
  for (int i = 4*t; i < VOUT; i += 4096){
    float4 v = *(const float4*)(row + i);
    m = fmaxf(m, fmaxf(fmaxf(v.x, v.y), fmaxf(v.z, v.w)));
  }
  #pragma unroll
  for (int o = 32; o; o >>= 1) m = fmaxf(m, __shfl_down(m, o));
  if (!lane) rm[w] = m;
  __syncthreads();
  float M = rm[0];
  #pragma unroll
  for (int i = 1; i < 16; ++i) M = fmaxf(M, rm[i]);
  float s = 0.f;
  for (int i = 4*t; i < VOUT; i += 4096){
    float4 v = *(const float4*)(row + i);
    s += expf(v.x-M) + expf(v.y-M) + expf(v.z-M) + expf(v.w-M);
  }
  #pragma unroll
  for (int o = 32; o; o >>= 1) s += __shfl_down(s, o);
  if (!lane) rs[w] = s;
  __syncthreads();
  float S = rs[0];
  #pragma unroll
  for (int i = 1; i < 16; ++i) S += rs[i];
  float inv = 1.f / S;
  for (int i = 4*t; i < VOUT; i += 4096){
    float4 v = *(const float4*)(row + i);
    v.x = expf(v.x-M)*inv; v.y = expf(v.y-M)*inv;
    v.z = expf(v.z-M)*inv; v.w = expf(v.w-M)*inv;
    *(float4*)(row + i) = v;
  }
}

extern "C" void kernel_launch(void* const* d_in, const int* in_sizes, int n_in,
                              void* d_out, int out_size, void* d_ws, size_t ws_size,
                              hipStream_t stream){
  (void)in_sizes; (void)n_in; (void)out_size;
  const int* idx   = (const int*)d_in[0];
  const void* enc  = d_in[1];
  const void* h1   = d_in[2];
  const void* c1   = d_in[3];
  const void* emb  = d_in[4];
  const void* mog1W= d_in[5];
  const void* mog1b= d_in[6];
  const void* Wih1 = d_in[7];
  const void* Whh1 = d_in[8];
  const void* bih1 = d_in[9];
  const void* bhh1 = d_in[10];
  // d_in[11] mog2_W: dead (layer-2 mogrifier h stays 0)
  const void* mog2b= d_in[12];
  const void* Wih2 = d_in[13];
  // d_in[14] lstm2_Whh: dead (h=0)
  const void* bih2 = d_in[15];
  const void* bhh2 = d_in[16];
  const void* fcW  = d_in[17];
  const void* fcb  = d_in[18];
  const void* ccW  = d_in[19];
  const void* ccb  = d_in[20];
  const void* outW = d_in[21];
  const void* outb = d_in[22];

  float* X    = (float*)d_ws;         // B*H  (x / h1n-scaled / concat_out)
  float* Hb   = X   + B*H;            // B*H  (h)
  float* H2   = Hb  + B*H;            // B*H  (h2)
  float* CAT  = H2  + B*H;            // B*2H (rnn_out | context)
  float* SC   = CAT + (size_t)B*2*H;  // B*SEQ (scratch, unused)
  int*  FLAG  = (int*)(SC + B*SEQ);   // 64 ints
  u16*  SAh   = (u16*)(FLAG + 64);    // B*H bf16 hi (X-role)
  u16*  SAl   = SAh + B*H;            // B*H bf16 lo
  u16*  SBh   = SAl + B*H;            // B*H bf16 hi (Hb-role)
  u16*  SBl   = SBh + B*H;            // B*H bf16 lo
  u16*  Xb    = SBl + B*H;            // B*H bf16 (concat_out for out-GEMM)
  float* P    = (float*)(Xb + B*H);   // split-K partials / attn partials

  int S1 = 16, S2 = 8;
  size_t need = ((size_t)(5*B*H + B*SEQ) + 64) * 4 + (size_t)B*H*2*5
              + (size_t)S2*B*4*H*4;
  if (ws_size < need) { S1 = 4; S2 = 1; }

  float* out_f = (float*)d_out;               // [B, VOUT] probs
  float* hid_f = out_f + (size_t)B * VOUT;    // [1, B, H] hidden

  k_detect<<<1, 256, 0, stream>>>((const u16*)enc, FLAG);
  k_init<<<B*H/256, 256, 0, stream>>>(idx, emb, h1, X, Hb, SAh, SAl, SBh, SBl, FLAG);

  // layer-1 mogrifier (MFMA 3-pass): i even -> x = 2sig(h@W^T+b)*x ; i odd -> h = ...
  for (int i = 0; i < 5; ++i){
    const u16 *ah, *al; float* c; u16 *ch, *cl;
    if (i & 1){ ah = SAh; al = SAl; c = Hb; ch = SBh; cl = SBl; }  // A = x, update h
    else      { ah = SBh; al = SBl; c = X;  ch = SAh; cl = SAl; }  // A = h, update x
    gemm3<1><<<dim3(H/64, S1), 256, 0, stream>>>(ah, al, nullptr, nullptr,
                                                 mog1W, nullptr, (size_t)i*H*H,
                                                 P, H, H/S1, H, FLAG);
    ep_gen<2><<<B*H/256, 256, 0, stream>>>(P, S1, mog1b, (size_t)i*H, c, H, ch, cl, FLAG);
  }

  // layer-1 LSTM gates (both operands in ONE launch) -> h1n-scaled into X (+splits SA)
  gemm3<2><<<dim3(4*H/64, S2), 256, 0, stream>>>(SAh, SAl, SBh, SBl,
                                                 Wih1, Whh1, 0,
                                                 P, H, H/S2, 4*H, FLAG);
  ep_lstm<<<B*H/256, 256, 0, stream>>>(P, S2, bih1, bhh1, c1, X, nullptr, mog2b,
                                       SAh, SAl, FLAG);

  // layer-2 LSTM (h=c=0) -> H2 (+splits SB) + f32 hidden out
  gemm3<1><<<dim3(4*H/64, S2), 256, 0, stream>>>(SAh, SAl, nullptr, nullptr,
                                                 Wih2, nullptr, 0,
                                                 P, H, H/S2, 4*H, FLAG);
  ep_lstm<<<B*H/256, 256, 0, stream>>>(P, S2, bih2, bhh2, nullptr, H2, hid_f, nullptr,
                                       SBh, SBl, FLAG);

  // fc -> rnn_out straight into CAT[:, 0:H]
  gemm3<1><<<dim3(H/64, S1), 256, 0, stream>>>(SBh, SBl, nullptr, nullptr,
                                               fcW, nullptr, 0,
                                               P, H, H/S1, H, FLAG);
  ep_gen<0><<<B*H/256, 256, 0, stream>>>(P, S1, fcb, 0, CAT, 2*H, nullptr, nullptr, FLAG);

  // flash attention: enc read once; 4 seq-partials combined into CAT[:, H:2H]
  float* Pctx = P;                      // NQ*B*H floats
  float* Pml  = P + (size_t)NQ*B*H;     // NQ*B*2 floats
  k_attn<<<B*NQ, 256, 0, stream>>>(CAT, enc, Pctx, Pml, FLAG);
  k_attn_fin<<<B*H/256, 256, 0, stream>>>(Pctx, Pml, CAT);

  // concat fc (K=2H, f32) -> X + Xb bf16 ; MFMA out logits -> d_out ; vocab softmax
  gemm_s<0><<<dim3(H/64, S1), 256, 0, stream>>>(CAT, ccW, 0, P, 2*H, 2*H/S1, H, FLAG);
  ep_gen<1><<<B*H/256, 256, 0, stream>>>(P, S1, ccb, 0, X, H, Xb, nullptr, FLAG);
  gemm_out_mfma<<<VOUT/64, 256, 0, stream>>>(Xb, outW, outb, out_f, FLAG);
  k_softmax_v<<<B, 1024, 0, stream>>>(out_f);
}